// Round 3
// baseline (576.419 us; speedup 1.0000x reference)
//
#include <hip/hip_runtime.h>
#include <hip/hip_bf16.h>
#include <math.h>

#define LRELU_ALPHA 0.2f

constexpr int B_ = 8;
constexpr int N_ = 2048;
constexpr int M_ = B_ * N_;      // 16384 rows total
constexpr int SEG = 32;          // ranks per segment for the vector scans
constexpr int NSEG = N_ / SEG;   // 64 segments per batch

// Device-scope release/acquire flags (workspace is re-poisoned each
// iteration -> flags are zeroed by an in-graph hipMemsetAsync node).
__device__ __forceinline__ void st_flag(int* p) {
    __hip_atomic_store(p, 1, __ATOMIC_RELEASE, __HIP_MEMORY_SCOPE_AGENT);
}
__device__ __forceinline__ void wait_flag(int* p) {
    while (__hip_atomic_load(p, __ATOMIC_ACQUIRE, __HIP_MEMORY_SCOPE_AGENT) == 0)
        __builtin_amdgcn_s_sleep(2);
}

// ---------------------------------------------------------------------------
// Kernel A: gemm (h = text@W, scores) + per-batch counting-rank continuation.
// 256 blocks x 256 threads, 1 block/CU -> all blocks resident -> the
// publish/poll handshake cannot deadlock.
// gemm: A-tile in LDS row-major [64][132] (conflict-free float4 staging
// writes, 2-way-free fragment reads); W read directly from global (L1/L2),
// keeping the LDS pipe for A only. 4x8 register tile, 4 waves.
// ---------------------------------------------------------------------------
__global__ __launch_bounds__(256) void kA(
    const float* __restrict__ text, const float* __restrict__ W,
    const float* __restrict__ a,
    float* __restrict__ h, float* __restrict__ s1, float* __restrict__ s2,
    float* __restrict__ eN0, float* __restrict__ eP0,
    int* __restrict__ perm, float* __restrict__ eNs, float* __restrict__ ePs,
    int* __restrict__ rank, float* __restrict__ ZN, float* __restrict__ ZP,
    int* __restrict__ flagA) {

    __shared__ __align__(16) union {
        float As[64 * 132];                      // 33792 B
        struct {
            float ls2[2048], leN[2048], leP[2048];
            float redn[256], redp[256];
            int   redc[256], redm[256];
        } k2;                                    // 28672 B
    } sm;

    const int tid = threadIdx.x;
    const int blk = blockIdx.x;
    const int b   = blk >> 5;        // batch
    const int eb  = blk & 31;        // 64-row tile within batch
    const int r0  = blk * 64;
    const int cx  = tid & 15;
    const int ry  = tid >> 4;
    const int c0  = cx * 4;
    const int c1  = 64 + cx * 4;
    const int rr0 = ry * 4;

    // ---- stage A tile (full K) ----
    for (int idx = tid; idx < 64 * 32; idx += 256) {
        int r = idx >> 5, k4 = (idx & 31) * 4;
        *(float4*)&sm.As[r * 132 + k4] =
            *(const float4*)&text[(size_t)(r0 + r) * 128 + k4];
    }
    __syncthreads();

    float acc[4][8];
#pragma unroll
    for (int i = 0; i < 4; ++i)
#pragma unroll
        for (int j = 0; j < 8; ++j) acc[i][j] = 0.f;

#pragma unroll 2
    for (int k0 = 0; k0 < 128; k0 += 4) {
        float4 av[4];
#pragma unroll
        for (int i = 0; i < 4; ++i)
            av[i] = *(const float4*)&sm.As[(rr0 + i) * 132 + k0];
#pragma unroll
        for (int kk = 0; kk < 4; ++kk) {
            float4 w0 = *(const float4*)&W[(size_t)(k0 + kk) * 128 + c0];
            float4 w1 = *(const float4*)&W[(size_t)(k0 + kk) * 128 + c1];
#pragma unroll
            for (int i = 0; i < 4; ++i) {
                const float avv = (kk == 0) ? av[i].x : (kk == 1) ? av[i].y
                                : (kk == 2) ? av[i].z : av[i].w;
                acc[i][0] += avv * w0.x; acc[i][1] += avv * w0.y;
                acc[i][2] += avv * w0.z; acc[i][3] += avv * w0.w;
                acc[i][4] += avv * w1.x; acc[i][5] += avv * w1.y;
                acc[i][6] += avv * w1.z; acc[i][7] += avv * w1.w;
            }
        }
    }

    // ---- epilogue: h stores + s1/s2/eN0/eP0 ----
    {
        float4 a1lo = *(const float4*)&a[c0];
        float4 a1hi = *(const float4*)&a[c1];
        float4 a2lo = *(const float4*)&a[128 + c0];
        float4 a2hi = *(const float4*)&a[128 + c1];
#pragma unroll
        for (int i = 0; i < 4; ++i) {
            const int row = r0 + rr0 + i;
            float4 o0 = {acc[i][0], acc[i][1], acc[i][2], acc[i][3]};
            float4 o1 = {acc[i][4], acc[i][5], acc[i][6], acc[i][7]};
            *(float4*)&h[(size_t)row * 128 + c0] = o0;
            *(float4*)&h[(size_t)row * 128 + c1] = o1;

            float p1 = o0.x*a1lo.x + o0.y*a1lo.y + o0.z*a1lo.z + o0.w*a1lo.w
                     + o1.x*a1hi.x + o1.y*a1hi.y + o1.z*a1hi.z + o1.w*a1hi.w;
            float p2 = o0.x*a2lo.x + o0.y*a2lo.y + o0.z*a2lo.z + o0.w*a2lo.w
                     + o1.x*a2hi.x + o1.y*a2hi.y + o1.z*a2hi.z + o1.w*a2hi.w;
#pragma unroll
            for (int off = 8; off >= 1; off >>= 1) {
                p1 += __shfl_xor(p1, off);
                p2 += __shfl_xor(p2, off);
            }
            if (cx == 0) {
                s1[row] = p1;
                s2[row] = p2;
                eN0[row] = expf(LRELU_ALPHA * p2);
                eP0[row] = expf(p2);
            }
        }
    }

    // ---- publish this tile's scores; wait for the whole batch ----
    __threadfence();
    __syncthreads();
    if (tid == 0) st_flag(&flagA[blk]);
    if (tid < 32) wait_flag(&flagA[b * 32 + tid]);
    __syncthreads();
    __threadfence();

    // ---- K2 continuation: counting rank for this block's 64 rows ----
    {
        const float4* g2 = (const float4*)(s2  + b * 2048);
        const float4* gn = (const float4*)(eN0 + b * 2048);
        const float4* gp = (const float4*)(eP0 + b * 2048);
        for (int t = tid; t < 512; t += 256) {
            ((float4*)sm.k2.ls2)[t] = g2[t];
            ((float4*)sm.k2.leN)[t] = gn[t];
            ((float4*)sm.k2.leP)[t] = gp[t];
        }
    }
    __syncthreads();

    {
        const int e = tid & 63;
        const int c = tid >> 6;           // chunk 0..3 of 512 elements
        const int i  = eb * 64 + e;
        const int gi = b * 2048 + i;
        const float myS2 = sm.k2.ls2[i];
        const float thr  = -s1[gi];

        int cnt = 0, mr = 0;
        float sn = 0.f, sp = 0.f;
        const int j0 = c * 512;
#pragma unroll 4
        for (int j = j0; j < j0 + 512; j += 4) {
            float4 v  = *(const float4*)&sm.k2.ls2[j];
            float4 en = *(const float4*)&sm.k2.leN[j];
            float4 ep = *(const float4*)&sm.k2.leP[j];
#define PROC(vv, ee, pp, jj)                                             \
            { bool le = (vv) <= thr;                                     \
              cnt += le ? 1 : 0;                                         \
              sn  += le ? (ee) : 0.f;                                    \
              sp  += le ? 0.f : (pp);                                    \
              mr  += ((vv) < myS2 || ((vv) == myS2 && (jj) < i)) ? 1 : 0; }
            PROC(v.x, en.x, ep.x, j + 0)
            PROC(v.y, en.y, ep.y, j + 1)
            PROC(v.z, en.z, ep.z, j + 2)
            PROC(v.w, en.w, ep.w, j + 3)
#undef PROC
        }
        sm.k2.redc[tid] = cnt; sm.k2.redm[tid] = mr;
        sm.k2.redn[tid] = sn;  sm.k2.redp[tid] = sp;
        __syncthreads();
        if (c == 0) {
            int tc = 0, tm = 0; float tn = 0.f, tp = 0.f;
#pragma unroll
            for (int cc = 0; cc < 4; ++cc) {
                tc += sm.k2.redc[cc * 64 + e];
                tm += sm.k2.redm[cc * 64 + e];
                tn += sm.k2.redn[cc * 64 + e];
                tp += sm.k2.redp[cc * 64 + e];
            }
            perm[b * 2048 + tm] = i;
            eNs [b * 2048 + tm] = sm.k2.leN[i];
            ePs [b * 2048 + tm] = sm.k2.leP[i];
            rank[gi] = tc;
            ZN[gi] = tn;
            ZP[gi] = tp;
        }
    }
}

// ---------------------------------------------------------------------------
// Kernel B: segment sums + prefix/suffix scan + output, one kernel.
// 1024 blocks x 128 threads = (b, s, dir); 4 blocks/CU x 2 waves -> all
// resident -> publish/poll cannot deadlock.
// Phase 1: own segment sum (32 products kept in registers), publish flag1.
// Phase 2: poll predecessor (dir=0) / successor (dir=1) segment flags,
//          accumulate base, write Pre/Suf (bf16), publish flag2.
// Phase 3: poll the batch's 128 flag2, then compute 16 output rows.
// ---------------------------------------------------------------------------
__global__ __launch_bounds__(128) void kB(
    const float* __restrict__ h, const int* __restrict__ perm,
    const float* __restrict__ eNs, const float* __restrict__ ePs,
    const float* __restrict__ s1, const int* __restrict__ rank,
    const float* __restrict__ ZN, const float* __restrict__ ZP,
    float* __restrict__ segN, float* __restrict__ segP,
    __hip_bfloat16* __restrict__ Pre, __hip_bfloat16* __restrict__ Suf,
    float* __restrict__ out,
    int* __restrict__ flag1, int* __restrict__ flag2) {

    const int blk = blockIdx.x;
    const int f   = threadIdx.x;
    const int b   = blk >> 7;
    const int t   = blk & 127;
    const int dir = t & 1;
    const int s   = t >> 1;
    const int rbase = s * SEG;

    // ---- Phase 1: own segment sum; keep the 32 products in registers ----
    const float* esrc = dir ? ePs : eNs;
    float prod[SEG];
    float segv = 0.f;
#pragma unroll
    for (int r = 0; r < SEG; ++r) {
        const int rr = b * 2048 + rbase + r;
        const float hv = h[(size_t)(b * 2048 + perm[rr]) * 128 + f];
        prod[r] = esrc[rr] * hv;
        segv += prod[r];
    }
    {
        float* seg = dir ? segP : segN;
        seg[(b * NSEG + s) * 128 + f] = segv;
    }
    __threadfence();
    __syncthreads();
    if (f == 0) st_flag(&flag1[b * 128 + t]);

    // ---- Phase 2: base accumulation + scan writes ----
    if (dir == 0) {
        if (f < s) wait_flag(&flag1[b * 128 + f * 2]);
        __syncthreads();
        __threadfence();
        float an = 0.f;
        for (int ss = 0; ss < s; ++ss)
            an += segN[(b * NSEG + ss) * 128 + f];
#pragma unroll
        for (int r = 0; r < SEG; ++r) {
            Pre[(size_t)(b * 2049 + rbase + r) * 128 + f] = __float2bfloat16(an);
            an += prod[r];
        }
        if (s == NSEG - 1)
            Pre[(size_t)(b * 2049 + 2048) * 128 + f] = __float2bfloat16(an);
    } else {
        if (f > s && f < NSEG) wait_flag(&flag1[b * 128 + f * 2 + 1]);
        __syncthreads();
        __threadfence();
        float ap = 0.f;
        for (int ss = s + 1; ss < NSEG; ++ss)
            ap += segP[(b * NSEG + ss) * 128 + f];
#pragma unroll
        for (int r = SEG - 1; r >= 0; --r) {
            ap += prod[r];
            Suf[(size_t)(b * 2049 + rbase + r) * 128 + f] = __float2bfloat16(ap);
        }
        if (s == NSEG - 1)
            Suf[(size_t)(b * 2049 + 2048) * 128 + f] = __float2bfloat16(0.f);
    }
    __threadfence();
    __syncthreads();
    if (f == 0) st_flag(&flag2[b * 128 + t]);

    // ---- Phase 3: wait for the whole batch's Pre/Suf, then 16 output rows --
    wait_flag(&flag2[b * 128 + f]);
    __syncthreads();
    __threadfence();

    const int i0 = b * 2048 + t * 16;
#pragma unroll 4
    for (int it = 0; it < 16; ++it) {
        const int i = i0 + it;
        const float s1v = s1[i];
        const float E1 = expf(s1v);
        const float E2 = expf(LRELU_ALPHA * s1v);
        const int   r  = rank[i];
        const float Z  = E1 * ZP[i] + E2 * ZN[i];
        const size_t o = (size_t)(b * 2049 + r) * 128 + f;
        const float hp = (E1 * __bfloat162float(Suf[o])
                        + E2 * __bfloat162float(Pre[o])) / Z;
        const float x = hp + LRELU_ALPHA * h[(size_t)i * 128 + f];
        out[(size_t)i * 128 + f] = (x > 0.f) ? x : expm1f(x);
    }
}

// ---------------------------------------------------------------------------
extern "C" void kernel_launch(void* const* d_in, const int* in_sizes, int n_in,
                              void* d_out, int out_size, void* d_ws, size_t ws_size,
                              hipStream_t stream) {
    const float* text = (const float*)d_in[0];
    // d_in[1] = adj : all-ones, unused by the reference math -> never read.
    const float* W = (const float*)d_in[2];
    const float* a = (const float*)d_in[3];
    float* out = (float*)d_out;

    // Flags first (one small memset node resets them every graph replay).
    int* flagA = (int*)d_ws;            // 256
    int* flag1 = flagA + 256;           // 1024
    int* flag2 = flag1 + 1024;          // 1024
    constexpr size_t FLAG_BYTES = 2304 * sizeof(int);

    float* p = (float*)((char*)d_ws + FLAG_BYTES);
    float* h    = p; p += (size_t)M_ * 128;
    float* s1   = p; p += M_;
    float* s2   = p; p += M_;
    float* eN0  = p; p += M_;
    float* eP0  = p; p += M_;
    int*   perm = (int*)p; p += M_;
    float* eNs  = p; p += M_;
    float* ePs  = p; p += M_;
    int*   rank = (int*)p; p += M_;
    float* ZN   = p; p += M_;
    float* ZP   = p; p += M_;
    float* segN = p; p += B_ * NSEG * 128;
    float* segP = p; p += B_ * NSEG * 128;
    __hip_bfloat16* Pre = (__hip_bfloat16*)p; p += (size_t)B_ * 2049 * 128 / 2;
    __hip_bfloat16* Suf = (__hip_bfloat16*)p; p += (size_t)B_ * 2049 * 128 / 2;

    hipMemsetAsync(flagA, 0, FLAG_BYTES, stream);
    hipLaunchKernelGGL(kA, dim3(256),  dim3(256), 0, stream,
                       text, W, a, h, s1, s2, eN0, eP0,
                       perm, eNs, ePs, rank, ZN, ZP, flagA);
    hipLaunchKernelGGL(kB, dim3(1024), dim3(128), 0, stream,
                       h, perm, eNs, ePs, s1, rank, ZN, ZP,
                       segN, segP, Pre, Suf, out, flag1, flag2);
}

// Round 4
// 267.660 us; speedup vs baseline: 2.1535x; 2.1535x over previous
//
#include <hip/hip_runtime.h>
#include <hip/hip_bf16.h>
#include <math.h>

#define LRELU_ALPHA 0.2f

constexpr int B_ = 8;
constexpr int N_ = 2048;
constexpr int M_ = B_ * N_;      // 16384 rows total
constexpr int SEG = 32;          // ranks per segment for the vector scans
constexpr int NSEG = N_ / SEG;   // 64 segments per batch

// ---------------------------------------------------------------------------
// K1: h = text @ W (fp32), fused epilogue: s1 = h·a1, s2 = h·a2,
//     eN0 = exp(0.2*s2), eP0 = exp(s2).
// 256 blocks x 256 threads (1 block/CU, 4 waves).
// A-tile in LDS row-major [64][132]: float4 staging writes are bank-linear
// (conflict-free); fragment reads are 4-address broadcasts (free).
// W is read straight from global (64 KB, L1/L2-resident, shared by all
// blocks) -> W traffic moves to the VMEM pipe, LDS pipe carries A only.
// Pipe model per CU: VALU ~8.2K cyc, LDS ~6K cyc, VMEM ~8K cyc -> ~5-6 us.
// (Structure identical to round-3 kA, which passed verification.)
// ---------------------------------------------------------------------------
__global__ __launch_bounds__(256) void k_gemm(const float* __restrict__ text,
                                              const float* __restrict__ W,
                                              const float* __restrict__ a,
                                              float* __restrict__ h,
                                              float* __restrict__ s1,
                                              float* __restrict__ s2,
                                              float* __restrict__ eN0,
                                              float* __restrict__ eP0) {
    __shared__ __align__(16) float As[64 * 132];

    const int tid = threadIdx.x;
    const int r0  = blockIdx.x * 64;
    const int cx  = tid & 15;
    const int ry  = tid >> 4;
    const int c0  = cx * 4;
    const int c1  = 64 + cx * 4;
    const int rr0 = ry * 4;

    // Stage A tile (full K): lanes write consecutive float4 -> conflict-free.
    for (int idx = tid; idx < 64 * 32; idx += 256) {
        int r = idx >> 5, k4 = (idx & 31) * 4;
        *(float4*)&As[r * 132 + k4] =
            *(const float4*)&text[(size_t)(r0 + r) * 128 + k4];
    }
    __syncthreads();

    float acc[4][8];
#pragma unroll
    for (int i = 0; i < 4; ++i)
#pragma unroll
        for (int j = 0; j < 8; ++j) acc[i][j] = 0.f;

#pragma unroll 2
    for (int k0 = 0; k0 < 128; k0 += 4) {
        float4 av[4];
#pragma unroll
        for (int i = 0; i < 4; ++i)
            av[i] = *(const float4*)&As[(rr0 + i) * 132 + k0];
#pragma unroll
        for (int kk = 0; kk < 4; ++kk) {
            float4 w0 = *(const float4*)&W[(size_t)(k0 + kk) * 128 + c0];
            float4 w1 = *(const float4*)&W[(size_t)(k0 + kk) * 128 + c1];
#pragma unroll
            for (int i = 0; i < 4; ++i) {
                const float avv = (kk == 0) ? av[i].x : (kk == 1) ? av[i].y
                                : (kk == 2) ? av[i].z : av[i].w;
                acc[i][0] += avv * w0.x; acc[i][1] += avv * w0.y;
                acc[i][2] += avv * w0.z; acc[i][3] += avv * w0.w;
                acc[i][4] += avv * w1.x; acc[i][5] += avv * w1.y;
                acc[i][6] += avv * w1.z; acc[i][7] += avv * w1.w;
            }
        }
    }

    float4 a1lo = *(const float4*)&a[c0];
    float4 a1hi = *(const float4*)&a[c1];
    float4 a2lo = *(const float4*)&a[128 + c0];
    float4 a2hi = *(const float4*)&a[128 + c1];

#pragma unroll
    for (int i = 0; i < 4; ++i) {
        const int row = r0 + rr0 + i;
        float4 o0 = {acc[i][0], acc[i][1], acc[i][2], acc[i][3]};
        float4 o1 = {acc[i][4], acc[i][5], acc[i][6], acc[i][7]};
        *(float4*)&h[(size_t)row * 128 + c0] = o0;
        *(float4*)&h[(size_t)row * 128 + c1] = o1;

        float p1 = o0.x*a1lo.x + o0.y*a1lo.y + o0.z*a1lo.z + o0.w*a1lo.w
                 + o1.x*a1hi.x + o1.y*a1hi.y + o1.z*a1hi.z + o1.w*a1hi.w;
        float p2 = o0.x*a2lo.x + o0.y*a2lo.y + o0.z*a2lo.z + o0.w*a2lo.w
                 + o1.x*a2hi.x + o1.y*a2hi.y + o1.z*a2hi.z + o1.w*a2hi.w;
#pragma unroll
        for (int off = 8; off >= 1; off >>= 1) {
            p1 += __shfl_xor(p1, off);
            p2 += __shfl_xor(p2, off);
        }
        if (cx == 0) {
            s1[row] = p1;
            s2[row] = p2;
            eN0[row] = expf(LRELU_ALPHA * p2);
            eP0[row] = expf(p2);
        }
    }
}

// ---------------------------------------------------------------------------
// K2: counting-rank kernel.
// ---------------------------------------------------------------------------
__global__ __launch_bounds__(512) void k_rank(const float* __restrict__ s2,
                                              const float* __restrict__ eN0,
                                              const float* __restrict__ eP0,
                                              const float* __restrict__ s1,
                                              int* __restrict__ perm,
                                              float* __restrict__ eNs,
                                              float* __restrict__ ePs,
                                              int* __restrict__ rank,
                                              float* __restrict__ ZN,
                                              float* __restrict__ ZP) {
    __shared__ float ls2[2048], leN[2048], leP[2048];
    __shared__ int   redc[512], redm[512];
    __shared__ float redn[512], redp[512];

    const int b  = blockIdx.x >> 5;
    const int eb = blockIdx.x & 31;
    const int tid = threadIdx.x;
    const int e = tid & 63;
    const int c = tid >> 6;            // chunk 0..7

    {
        const float4* g2 = (const float4*)(s2  + b * 2048);
        const float4* gn = (const float4*)(eN0 + b * 2048);
        const float4* gp = (const float4*)(eP0 + b * 2048);
        ((float4*)ls2)[tid] = g2[tid];
        ((float4*)leN)[tid] = gn[tid];
        ((float4*)leP)[tid] = gp[tid];
    }
    __syncthreads();

    const int i  = eb * 64 + e;
    const int gi = b * 2048 + i;
    const float myS2 = ls2[i];
    const float thr  = -s1[gi];

    int cnt = 0, mr = 0;
    float sn = 0.f, sp = 0.f;
    const int j0 = c * 256;
#pragma unroll 4
    for (int j = j0; j < j0 + 256; j += 4) {
        float4 v  = *(const float4*)&ls2[j];
        float4 en = *(const float4*)&leN[j];
        float4 ep = *(const float4*)&leP[j];
#define PROC(vv, ee, pp, jj)                                             \
        { bool le = (vv) <= thr;                                         \
          cnt += le ? 1 : 0;                                             \
          sn  += le ? (ee) : 0.f;                                        \
          sp  += le ? 0.f : (pp);                                        \
          mr  += ((vv) < myS2 || ((vv) == myS2 && (jj) < i)) ? 1 : 0; }
        PROC(v.x, en.x, ep.x, j + 0)
        PROC(v.y, en.y, ep.y, j + 1)
        PROC(v.z, en.z, ep.z, j + 2)
        PROC(v.w, en.w, ep.w, j + 3)
#undef PROC
    }
    redc[tid] = cnt; redm[tid] = mr; redn[tid] = sn; redp[tid] = sp;
    __syncthreads();
    if (c == 0) {
        int tc = 0, tm = 0; float tn = 0.f, tp = 0.f;
#pragma unroll
        for (int cc = 0; cc < 8; ++cc) {
            tc += redc[cc * 64 + e];
            tm += redm[cc * 64 + e];
            tn += redn[cc * 64 + e];
            tp += redp[cc * 64 + e];
        }
        perm[b * 2048 + tm] = i;
        eNs [b * 2048 + tm] = leN[i];
        ePs [b * 2048 + tm] = leP[i];
        rank[gi] = tc;
        ZN[gi] = tn;
        ZP[gi] = tp;
    }
}

// ---------------------------------------------------------------------------
// K3: per (batch, segment) sums of eNs*h[perm] and ePs*h[perm].
// ---------------------------------------------------------------------------
__global__ __launch_bounds__(128) void k_segsum(const float* __restrict__ h,
                                                const int* __restrict__ perm,
                                                const float* __restrict__ eNs,
                                                const float* __restrict__ ePs,
                                                float* __restrict__ segN,
                                                float* __restrict__ segP) {
    const int blk = blockIdx.x;
    const int b = blk >> 6, s = blk & 63;
    const int f = threadIdx.x;
    const int rbase = s * SEG;
    float an = 0.f, ap = 0.f;
#pragma unroll 4
    for (int r = 0; r < SEG; ++r) {
        int rr = b * 2048 + rbase + r;
        float hv = h[(size_t)(b * 2048 + perm[rr]) * 128 + f];
        an += eNs[rr] * hv;
        ap += ePs[rr] * hv;
    }
    segN[blk * 128 + f] = an;
    segP[blk * 128 + f] = ap;
}

// ---------------------------------------------------------------------------
// K4: full vector prefix/suffix arrays, stored BF16 (accumulated fp32).
// Forward (Pre) and backward (Suf) scans in SEPARATE blocks.
//   Pre[b][r][f] = sum_{k<r}  eNs[k]*h[perm[k]][f]   (r in [0,2048])
//   Suf[b][r][f] = sum_{k>=r} ePs[k]*h[perm[k]][f]
// ---------------------------------------------------------------------------
__global__ __launch_bounds__(128) void k_prefix(const float* __restrict__ h,
                                                const int* __restrict__ perm,
                                                const float* __restrict__ eNs,
                                                const float* __restrict__ ePs,
                                                const float* __restrict__ segN,
                                                const float* __restrict__ segP,
                                                __hip_bfloat16* __restrict__ Pre,
                                                __hip_bfloat16* __restrict__ Suf) {
    const int blk  = blockIdx.x;
    const int dir  = blk & 1;
    const int task = blk >> 1;
    const int b = task >> 6, s = task & 63;
    const int f = threadIdx.x;
    const int rbase = s * SEG;

    if (dir == 0) {
        float an = 0.f;
        for (int ss = 0; ss < s; ++ss) an += segN[(b * NSEG + ss) * 128 + f];
#pragma unroll 4
        for (int r = 0; r < SEG; ++r) {
            int rr = b * 2048 + rbase + r;
            Pre[(size_t)(b * 2049 + rbase + r) * 128 + f] = __float2bfloat16(an);
            an += eNs[rr] * h[(size_t)(b * 2048 + perm[rr]) * 128 + f];
        }
        if (s == NSEG - 1)
            Pre[(size_t)(b * 2049 + 2048) * 128 + f] = __float2bfloat16(an);
    } else {
        float ap = 0.f;
        for (int ss = s + 1; ss < NSEG; ++ss) ap += segP[(b * NSEG + ss) * 128 + f];
#pragma unroll 4
        for (int r = SEG - 1; r >= 0; --r) {
            int rr = b * 2048 + rbase + r;
            ap += ePs[rr] * h[(size_t)(b * 2048 + perm[rr]) * 128 + f];
            Suf[(size_t)(b * 2049 + rbase + r) * 128 + f] = __float2bfloat16(ap);
        }
        if (s == NSEG - 1)
            Suf[(size_t)(b * 2049 + 2048) * 128 + f] = __float2bfloat16(0.f);
    }
}

// ---------------------------------------------------------------------------
// K5: out = elu(h' + 0.2 h),  h' = (E1*Suf[r] + E2*Pre[r]) / (E1*ZP + E2*ZN)
// ---------------------------------------------------------------------------
__global__ __launch_bounds__(256) void k_out(const float* __restrict__ h,
                                             const float* __restrict__ s1,
                                             const int* __restrict__ rank,
                                             const float* __restrict__ ZN,
                                             const float* __restrict__ ZP,
                                             const __hip_bfloat16* __restrict__ Pre,
                                             const __hip_bfloat16* __restrict__ Suf,
                                             float* __restrict__ out) {
    const int tid = threadIdx.x;
    const int lr = tid >> 7, f = tid & 127;
    const int i = blockIdx.x * 2 + lr;
    const int b = i >> 11;

    const float s1v = s1[i];
    const float E1 = expf(s1v);
    const float E2 = expf(LRELU_ALPHA * s1v);
    const int   r  = rank[i];
    const float Z  = E1 * ZP[i] + E2 * ZN[i];
    const size_t o = (size_t)(b * 2049 + r) * 128 + f;
    const float hp = (E1 * __bfloat162float(Suf[o]) + E2 * __bfloat162float(Pre[o])) / Z;
    const float x = hp + LRELU_ALPHA * h[(size_t)i * 128 + f];
    out[(size_t)i * 128 + f] = (x > 0.f) ? x : expm1f(x);
}

// ---------------------------------------------------------------------------
extern "C" void kernel_launch(void* const* d_in, const int* in_sizes, int n_in,
                              void* d_out, int out_size, void* d_ws, size_t ws_size,
                              hipStream_t stream) {
    const float* text = (const float*)d_in[0];
    // d_in[1] = adj : all-ones, unused by the reference math -> never read.
    const float* W = (const float*)d_in[2];
    const float* a = (const float*)d_in[3];
    float* out = (float*)d_out;

    float* p = (float*)d_ws;
    float* h    = p; p += (size_t)M_ * 128;
    float* s1   = p; p += M_;
    float* s2   = p; p += M_;
    float* eN0  = p; p += M_;
    float* eP0  = p; p += M_;
    int*   perm = (int*)p; p += M_;
    float* eNs  = p; p += M_;
    float* ePs  = p; p += M_;
    int*   rank = (int*)p; p += M_;
    float* ZN   = p; p += M_;
    float* ZP   = p; p += M_;
    float* segN = p; p += B_ * NSEG * 128;
    float* segP = p; p += B_ * NSEG * 128;
    __hip_bfloat16* Pre = (__hip_bfloat16*)p; p += (size_t)B_ * 2049 * 128 / 2;
    __hip_bfloat16* Suf = (__hip_bfloat16*)p; p += (size_t)B_ * 2049 * 128 / 2;

    hipLaunchKernelGGL(k_gemm,   dim3(M_ / 64),       dim3(256), 0, stream,
                       text, W, a, h, s1, s2, eN0, eP0);
    hipLaunchKernelGGL(k_rank,   dim3(B_ * 32),       dim3(512), 0, stream,
                       s2, eN0, eP0, s1, perm, eNs, ePs, rank, ZN, ZP);
    hipLaunchKernelGGL(k_segsum, dim3(B_ * NSEG),     dim3(128), 0, stream,
                       h, perm, eNs, ePs, segN, segP);
    hipLaunchKernelGGL(k_prefix, dim3(B_ * NSEG * 2), dim3(128), 0, stream,
                       h, perm, eNs, ePs, segN, segP, Pre, Suf);
    hipLaunchKernelGGL(k_out,    dim3(M_ / 2),        dim3(256), 0, stream,
                       h, s1, rank, ZN, ZP, Pre, Suf, out);
}

// Round 6
// 244.488 us; speedup vs baseline: 2.3577x; 1.0948x over previous
//
#include <hip/hip_runtime.h>
#include <hip/hip_bf16.h>
#include <math.h>

#define LRELU_ALPHA 0.2f

constexpr int B_ = 8;
constexpr int N_ = 2048;
constexpr int M_ = B_ * N_;      // 16384 rows total
constexpr int SEG = 32;          // ranks per segment
constexpr int NSEG = N_ / SEG;   // 64 segments per batch

// ---------------------------------------------------------------------------
// K1: h = text @ W (fp32) + fused scores s1,s2, eN0=exp(0.2*s2), eP0=exp(s2).
// 256 blocks x 256 threads (1 block/CU, 4 waves).
// Best-of-both from R0..R4 A/B evidence:
//   - As row-major [64][132]: float4 staging writes bank-linear (conflict-
//     free, R4-verified); fragment reads broadcast (free).
//   - W staged FULL-K in LDS (R4 proved global-W costs +33 us: 64KB > L1).
//     Ws reads at 16B lane stride -> 2-way (free).
// One __syncthreads total. LDS = 99.3 KB (gfx950 allows up to 160 KB/WG).
// Block 0 also zeroes ALL 512 bucket counters (R5 crash: only 256 of 512
// were zeroed -> poisoned atomicAdd -> OOB bucket store -> memory fault).
// ---------------------------------------------------------------------------
__global__ __launch_bounds__(256) void k_gemm(const float* __restrict__ text,
                                              const float* __restrict__ W,
                                              const float* __restrict__ a,
                                              float* __restrict__ h,
                                              float* __restrict__ s1,
                                              float* __restrict__ s2,
                                              float* __restrict__ eN0,
                                              float* __restrict__ eP0,
                                              int* __restrict__ bcnt) {
    __shared__ __align__(16) float As[64 * 132];
    __shared__ __align__(16) float Ws[128 * 128];

    const int tid = threadIdx.x;
    const int blk = blockIdx.x;

    if (blk == 0)                              // K2 runs after K1 completes
        for (int t = tid; t < B_ * NSEG; t += 256) bcnt[t] = 0;

    const int r0  = blk * 64;
    const int cx  = tid & 15;
    const int ry  = tid >> 4;
    const int c0  = cx * 4;
    const int c1  = 64 + cx * 4;
    const int rr0 = ry * 4;

    // Stage A (64x128) row-major, stride 132: float4 writes, conflict-free.
    for (int idx = tid; idx < 64 * 32; idx += 256) {
        int r = idx >> 5, k4 = (idx & 31) * 4;
        *(float4*)&As[r * 132 + k4] =
            *(const float4*)&text[(size_t)(r0 + r) * 128 + k4];
    }
    // Stage W (128x128) linear: float4 writes, conflict-free.
    for (int idx = tid; idx < 128 * 32; idx += 256) {
        int k = idx >> 5, f4 = (idx & 31) * 4;
        *(float4*)&Ws[k * 128 + f4] = *(const float4*)&W[(size_t)k * 128 + f4];
    }
    __syncthreads();

    float acc[4][8];
#pragma unroll
    for (int i = 0; i < 4; ++i)
#pragma unroll
        for (int j = 0; j < 8; ++j) acc[i][j] = 0.f;

#pragma unroll 2
    for (int k0 = 0; k0 < 128; k0 += 4) {
        float4 av[4];
#pragma unroll
        for (int i = 0; i < 4; ++i)
            av[i] = *(const float4*)&As[(rr0 + i) * 132 + k0];  // broadcast
#pragma unroll
        for (int kk = 0; kk < 4; ++kk) {
            float4 w0 = *(const float4*)&Ws[(k0 + kk) * 128 + c0];  // free
            float4 w1 = *(const float4*)&Ws[(k0 + kk) * 128 + c1];
#pragma unroll
            for (int i = 0; i < 4; ++i) {
                const float avv = (kk == 0) ? av[i].x : (kk == 1) ? av[i].y
                                : (kk == 2) ? av[i].z : av[i].w;
                acc[i][0] += avv * w0.x; acc[i][1] += avv * w0.y;
                acc[i][2] += avv * w0.z; acc[i][3] += avv * w0.w;
                acc[i][4] += avv * w1.x; acc[i][5] += avv * w1.y;
                acc[i][6] += avv * w1.z; acc[i][7] += avv * w1.w;
            }
        }
    }

    float4 a1lo = *(const float4*)&a[c0];
    float4 a1hi = *(const float4*)&a[c1];
    float4 a2lo = *(const float4*)&a[128 + c0];
    float4 a2hi = *(const float4*)&a[128 + c1];

#pragma unroll
    for (int i = 0; i < 4; ++i) {
        const int row = r0 + rr0 + i;
        float4 o0 = {acc[i][0], acc[i][1], acc[i][2], acc[i][3]};
        float4 o1 = {acc[i][4], acc[i][5], acc[i][6], acc[i][7]};
        *(float4*)&h[(size_t)row * 128 + c0] = o0;
        *(float4*)&h[(size_t)row * 128 + c1] = o1;

        float p1 = o0.x*a1lo.x + o0.y*a1lo.y + o0.z*a1lo.z + o0.w*a1lo.w
                 + o1.x*a1hi.x + o1.y*a1hi.y + o1.z*a1hi.z + o1.w*a1hi.w;
        float p2 = o0.x*a2lo.x + o0.y*a2lo.y + o0.z*a2lo.z + o0.w*a2lo.w
                 + o1.x*a2hi.x + o1.y*a2hi.y + o1.z*a2hi.z + o1.w*a2hi.w;
#pragma unroll
        for (int off = 8; off >= 1; off >>= 1) {
            p1 += __shfl_xor(p1, off);
            p2 += __shfl_xor(p2, off);
        }
        if (cx == 0) {
            s1[row] = p1;
            s2[row] = p2;
            eN0[row] = expf(LRELU_ALPHA * p2);
            eP0[row] = expf(p2);
        }
    }
}

// ---------------------------------------------------------------------------
// K2: counting rank + sorted-order arrays + rank-segment buckets.
// bucket entry packs row index (11b) | rank tc (12b, <<11). tc in [0,2048];
// seg = min(tc>>5, 63) so the tc==2048 edge lands at position 32 of seg 63.
// Bucket capacity is 2048 (tc is a per-row count, not a permutation — many
// rows can share a segment). pos clamp: overflow degrades to a visible
// absmax failure instead of an OOB fault.
// ---------------------------------------------------------------------------
__global__ __launch_bounds__(512) void k_rank(const float* __restrict__ s2,
                                              const float* __restrict__ eN0,
                                              const float* __restrict__ eP0,
                                              const float* __restrict__ s1,
                                              int* __restrict__ perm,
                                              float* __restrict__ eNs,
                                              float* __restrict__ ePs,
                                              float* __restrict__ ZN,
                                              float* __restrict__ ZP,
                                              int* __restrict__ bcnt,
                                              int* __restrict__ bucket) {
    __shared__ float ls2[2048], leN[2048], leP[2048];
    __shared__ int   redc[512], redm[512];
    __shared__ float redn[512], redp[512];

    const int b  = blockIdx.x >> 5;
    const int eb = blockIdx.x & 31;
    const int tid = threadIdx.x;
    const int e = tid & 63;
    const int c = tid >> 6;            // chunk 0..7

    {
        const float4* g2 = (const float4*)(s2  + b * 2048);
        const float4* gn = (const float4*)(eN0 + b * 2048);
        const float4* gp = (const float4*)(eP0 + b * 2048);
        ((float4*)ls2)[tid] = g2[tid];
        ((float4*)leN)[tid] = gn[tid];
        ((float4*)leP)[tid] = gp[tid];
    }
    __syncthreads();

    const int i  = eb * 64 + e;
    const int gi = b * 2048 + i;
    const float myS2 = ls2[i];
    const float thr  = -s1[gi];

    int cnt = 0, mr = 0;
    float sn = 0.f, sp = 0.f;
    const int j0 = c * 256;
#pragma unroll 4
    for (int j = j0; j < j0 + 256; j += 4) {
        float4 v  = *(const float4*)&ls2[j];
        float4 en = *(const float4*)&leN[j];
        float4 ep = *(const float4*)&leP[j];
#define PROC(vv, ee, pp, jj)                                             \
        { bool le = (vv) <= thr;                                         \
          cnt += le ? 1 : 0;                                             \
          sn  += le ? (ee) : 0.f;                                        \
          sp  += le ? 0.f : (pp);                                        \
          mr  += ((vv) < myS2 || ((vv) == myS2 && (jj) < i)) ? 1 : 0; }
        PROC(v.x, en.x, ep.x, j + 0)
        PROC(v.y, en.y, ep.y, j + 1)
        PROC(v.z, en.z, ep.z, j + 2)
        PROC(v.w, en.w, ep.w, j + 3)
#undef PROC
    }
    redc[tid] = cnt; redm[tid] = mr; redn[tid] = sn; redp[tid] = sp;
    __syncthreads();
    if (c == 0) {
        int tc = 0, tm = 0; float tn = 0.f, tp = 0.f;
#pragma unroll
        for (int cc = 0; cc < 8; ++cc) {
            tc += redc[cc * 64 + e];
            tm += redm[cc * 64 + e];
            tn += redn[cc * 64 + e];
            tp += redp[cc * 64 + e];
        }
        perm[b * 2048 + tm] = i;
        eNs [b * 2048 + tm] = leN[i];
        ePs [b * 2048 + tm] = leP[i];
        ZN[gi] = tn;
        ZP[gi] = tp;
        const int seg = min(tc >> 5, NSEG - 1);
        const int pos = atomicAdd(&bcnt[b * NSEG + seg], 1);
        if (pos < 2048)
            bucket[(b * NSEG + seg) * 2048 + pos] = i | (tc << 11);
    }
}

// ---------------------------------------------------------------------------
// K3: per (batch, segment) sums of eNs*h[perm] and ePs*h[perm].
// Gather fully unrolled: all 32 row-loads issued independently.
// ---------------------------------------------------------------------------
__global__ __launch_bounds__(128) void k_segsum(const float* __restrict__ h,
                                                const int* __restrict__ perm,
                                                const float* __restrict__ eNs,
                                                const float* __restrict__ ePs,
                                                float* __restrict__ segN,
                                                float* __restrict__ segP) {
    const int blk = blockIdx.x;
    const int b = blk >> 6, s = blk & 63;
    const int f = threadIdx.x;
    const int rr0 = b * 2048 + s * SEG;

    int pm[SEG];
#pragma unroll
    for (int r = 0; r < SEG; ++r) pm[r] = perm[rr0 + r];
    float hv[SEG];
#pragma unroll
    for (int r = 0; r < SEG; ++r)
        hv[r] = h[(size_t)(b * 2048 + pm[r]) * 128 + f];

    float an = 0.f, ap = 0.f;
#pragma unroll
    for (int r = 0; r < SEG; ++r) {
        an += eNs[rr0 + r] * hv[r];
        ap += ePs[rr0 + r] * hv[r];
    }
    segN[blk * 128 + f] = an;
    segP[blk * 128 + f] = ap;
}

// ---------------------------------------------------------------------------
// K4': segment-local prefix AND suffix vectors in LDS (fp32), then directly
// emit output rows whose rank falls in this segment (from K2's buckets).
// Replaces old K4 (bf16 Pre/Suf materialization, 8.4MB W) + K5 (8.4MB R).
//   anL[j] = Pre[s*32+j] = sum_{k < s*32+j} eNs[k]*h[perm[k]]   j in [0,32]
//   apL[j] = Suf[s*32+j] = sum_{k >= s*32+j} ePs[k]*h[perm[k]]
// Row i with rank tc in this segment: pl = tc - s*32 (in [0,32]),
//   h' = (E1*apL[pl] + E2*anL[pl]) / (E1*ZP + E2*ZN),  out = elu(h' + 0.2 h).
// ---------------------------------------------------------------------------
__global__ __launch_bounds__(128) void k_scanout(
    const float* __restrict__ h, const int* __restrict__ perm,
    const float* __restrict__ eNs, const float* __restrict__ ePs,
    const float* __restrict__ s1,
    const float* __restrict__ ZN, const float* __restrict__ ZP,
    const float* __restrict__ segN, const float* __restrict__ segP,
    const int* __restrict__ bcnt, const int* __restrict__ bucket,
    float* __restrict__ out) {

    __shared__ float anL[(SEG + 1) * 128];
    __shared__ float apL[(SEG + 1) * 128];

    const int blk = blockIdx.x;
    const int b = blk >> 6, s = blk & 63;
    const int f = threadIdx.x;

    // Cross-segment bases (coalesced, independent loads).
    float bn = 0.f, bp = 0.f;
    for (int ss = 0; ss < s; ++ss)        bn += segN[(b * NSEG + ss) * 128 + f];
    for (int ss = s + 1; ss < NSEG; ++ss) bp += segP[(b * NSEG + ss) * 128 + f];

    // Gather this segment's 32 rows (fully unrolled, loads all in flight).
    const int rr0 = b * 2048 + s * SEG;
    int pm[SEG];
#pragma unroll
    for (int r = 0; r < SEG; ++r) pm[r] = perm[rr0 + r];
    float hv[SEG];
#pragma unroll
    for (int r = 0; r < SEG; ++r)
        hv[r] = h[(size_t)(b * 2048 + pm[r]) * 128 + f];

    // Forward scan -> anL, backward scan -> apL (fp32, in LDS).
    float an = bn;
#pragma unroll
    for (int r = 0; r < SEG; ++r) {
        anL[r * 128 + f] = an;
        an += eNs[rr0 + r] * hv[r];
    }
    anL[SEG * 128 + f] = an;

    float ap = bp;
    apL[SEG * 128 + f] = ap;
#pragma unroll
    for (int r = SEG - 1; r >= 0; --r) {
        ap += ePs[rr0 + r] * hv[r];
        apL[r * 128 + f] = ap;
    }
    __syncthreads();

    // Emit output rows bucketed to this segment (bucket read is wave-uniform).
    const int m = min(bcnt[b * NSEG + s], 2048);
    for (int t = 0; t < m; ++t) {
        const int packed = bucket[(b * NSEG + s) * 2048 + t];
        const int il = packed & 2047;
        const int tc = packed >> 11;
        const int gi = b * 2048 + il;
        const int pl = tc - s * SEG;        // in [0,32]
        const float s1v = s1[gi];
        const float E1 = expf(s1v);
        const float E2 = expf(LRELU_ALPHA * s1v);
        const float Z  = E1 * ZP[gi] + E2 * ZN[gi];
        const float hp = (E1 * apL[pl * 128 + f] + E2 * anL[pl * 128 + f]) / Z;
        const float x  = hp + LRELU_ALPHA * h[(size_t)gi * 128 + f];
        out[(size_t)gi * 128 + f] = (x > 0.f) ? x : expm1f(x);
    }
}

// ---------------------------------------------------------------------------
extern "C" void kernel_launch(void* const* d_in, const int* in_sizes, int n_in,
                              void* d_out, int out_size, void* d_ws, size_t ws_size,
                              hipStream_t stream) {
    const float* text = (const float*)d_in[0];
    // d_in[1] = adj : all-ones, unused by the reference math -> never read.
    const float* W = (const float*)d_in[2];
    const float* a = (const float*)d_in[3];
    float* out = (float*)d_out;

    float* p = (float*)d_ws;
    float* h    = p; p += (size_t)M_ * 128;
    float* s1   = p; p += M_;
    float* s2   = p; p += M_;
    float* eN0  = p; p += M_;
    float* eP0  = p; p += M_;
    int*   perm = (int*)p; p += M_;
    float* eNs  = p; p += M_;
    float* ePs  = p; p += M_;
    float* ZN   = p; p += M_;
    float* ZP   = p; p += M_;
    float* segN = p; p += B_ * NSEG * 128;
    float* segP = p; p += B_ * NSEG * 128;
    int*   bcnt = (int*)p; p += B_ * NSEG;
    int*   bucket = (int*)p; p += (size_t)B_ * NSEG * 2048;

    hipLaunchKernelGGL(k_gemm,   dim3(M_ / 64),   dim3(256), 0, stream,
                       text, W, a, h, s1, s2, eN0, eP0, bcnt);
    hipLaunchKernelGGL(k_rank,   dim3(B_ * 32),   dim3(512), 0, stream,
                       s2, eN0, eP0, s1, perm, eNs, ePs, ZN, ZP, bcnt, bucket);
    hipLaunchKernelGGL(k_segsum, dim3(B_ * NSEG), dim3(128), 0, stream,
                       h, perm, eNs, ePs, segN, segP);
    hipLaunchKernelGGL(k_scanout, dim3(B_ * NSEG), dim3(128), 0, stream,
                       h, perm, eNs, ePs, s1, ZN, ZP, segN, segP,
                       bcnt, bucket, out);
}